// Round 1
// baseline (198.243 us; speedup 1.0000x reference)
//
#include <hip/hip_runtime.h>
#include <hip/hip_bf16.h>
#include <math.h>

// Re(C)[4096,8192] = Re( (softplus(W)*tau*cis(-2pi*j*k/4096)) @ FFT(softplus(H)) )
// Pipeline:
//   K1 make_A    : A2[4096][512] bf16 (Re,Im interleaved)          -> ws[0..4MB)
//   K2 fft_H     : per-row 8192-pt FFT of softplus(H), packed bf16
//                  (Hr, -Hi) per uint, layout [k][c]               -> d_out[0..8MB)
//   K3 transpose : Hc[k][c] -> Hc_t[c][k] (1KB rows)               -> ws[4MB..12MB)
//   K4 gemm      : 256x256 phase-split bf16 MFMA GEMM (T1 XCD swizzle,
//                  T2 LDS xor-swizzle, T3/T4 counted vmcnt(8) depth-2
//                  pipeline, T5 setprio), K=512                    -> d_out (128MB)
// All ws reads clamped, ws writes guarded, epilogue guarded: fault-free.

#define NROW 4096
#define RANKN 256
#define NCOL 8192
#define PI_F 3.14159265358979323846f

#define A2_U   (NROW * RANKN)            // 1M uints = 4MB  (A2 region, ws)
#define HT_OFF A2_U                      // Hc_t offset in ws (uints)
#define HT_U   (NCOL * RANKN)            // 2M uints = 8MB
#define WS_NEED (A2_U + HT_U)            // 3M uints = 12MB

typedef __attribute__((ext_vector_type(8))) short short8;
typedef __attribute__((ext_vector_type(4))) float floatx4;

__device__ static inline unsigned short f2bf(float f) {
    union { float f; unsigned int u; } v; v.f = f;
    unsigned int r = v.u + 0x7FFFu + ((v.u >> 16) & 1u);  // RNE
    return (unsigned short)(r >> 16);
}

__device__ static inline float softplus_f(float x) {
    return __logf(1.0f + __expf(x));   // inputs uniform[0,1): safe
}

// ===========================================================================
// K1: A2[j][k'] packed uints: (Re | Im<<16) of softplus(W)*tau*cis(-2pi jk/4096)
// ===========================================================================
__global__ __launch_bounds__(256) void make_A(const float* __restrict__ W,
                                              const float* __restrict__ tau,
                                              unsigned int* __restrict__ ws,
                                              unsigned int ws_uints) {
    const int j = blockIdx.x;
    const int k = threadIdx.x;
    const unsigned int idx = j * RANKN + k;
    const float st = softplus_f(W[idx]) * tau[idx];
    const int   m  = (j * k) & (NROW - 1);
    const float ang = (float)m * (-2.0f * PI_F / (float)NROW);
    const unsigned int v = (unsigned int)f2bf(st * __cosf(ang)) |
                           ((unsigned int)f2bf(st * __sinf(ang)) << 16);
    if (idx < ws_uints) ws[idx] = v;
}

// ===========================================================================
// K2: per-row 8192-pt FFT, radix 8*8*8*16, 1024 threads, 64KB LDS.
// Output packed (Hr | (-Hi)<<16) uints, layout [k][c], into d_out[0..2M uints).
// ===========================================================================
#define SW(i) ((i) ^ (((i) >> 5) & 31))

__device__ constexpr int brev_c(int x, int bits) {
    int r = 0;
    for (int i = 0; i < bits; ++i) r |= ((x >> i) & 1) << (bits - 1 - i);
    return r;
}

__device__ static inline void fft8_reg(float re[8], float im[8]) {
#pragma unroll
    for (int s = 1; s <= 3; ++s) {
        const int half = 1 << (s - 1);
#pragma unroll
        for (int b = 0; b < 4; ++b) {
            const int p  = b & (half - 1);
            const int g  = b >> (s - 1);
            const int i1 = (g << s) + p;
            const int i2 = i1 + half;
            const float ang = -PI_F * (float)p / (float)half;
            const float cw = __cosf(ang), sw = __sinf(ang);
            const float tr = cw * re[i2] - sw * im[i2];
            const float ti = cw * im[i2] + sw * re[i2];
            re[i2] = re[i1] - tr; im[i2] = im[i1] - ti;
            re[i1] += tr;         im[i1] += ti;
        }
    }
}

__device__ static inline void fft16_reg(float re[16], float im[16]) {
#pragma unroll
    for (int s = 1; s <= 4; ++s) {
        const int half = 1 << (s - 1);
#pragma unroll
        for (int b = 0; b < 8; ++b) {
            const int p  = b & (half - 1);
            const int g  = b >> (s - 1);
            const int i1 = (g << s) + p;
            const int i2 = i1 + half;
            const float ang = -PI_F * (float)p / (float)half;
            const float cw = __cosf(ang), sw = __sinf(ang);
            const float tr = cw * re[i2] - sw * im[i2];
            const float ti = cw * im[i2] + sw * re[i2];
            re[i2] = re[i1] - tr; im[i2] = im[i1] - ti;
            re[i1] += tr;         im[i1] += ti;
        }
    }
}

__global__ __launch_bounds__(1024) void fft_H(const float* __restrict__ H,
                                              unsigned int* __restrict__ Hc,
                                              unsigned int out_uints) {
    __shared__ float2 buf[8192];   // 64 KB
    const int t = threadIdx.x;     // 0..1023
    const int row = blockIdx.x;    // rank index
    const float* h = H + (size_t)row * NCOL;

    // load softplus(H row)
#pragma unroll
    for (int e = 0; e < 8; ++e) {
        const int n = t + 1024 * e;
        buf[SW(n)] = make_float2(softplus_f(h[n]), 0.0f);
    }
    __syncthreads();

    // L1: FFT-8 over a (stride 1024), twiddle W_8192^(t*a')
    {
        float re[8], im[8];
#pragma unroll
        for (int a = 0; a < 8; ++a) {
            const float2 v = buf[SW(1024 * a + t)];
            re[brev_c(a, 3)] = v.x; im[brev_c(a, 3)] = v.y;
        }
        fft8_reg(re, im);
#pragma unroll
        for (int ap = 0; ap < 8; ++ap) {
            const float ang = (-2.0f * PI_F / 8192.0f) * (float)(t * ap);
            const float cw = __cosf(ang), sw = __sinf(ang);
            buf[SW(ap * 1024 + t)] =
                make_float2(cw * re[ap] - sw * im[ap], cw * im[ap] + sw * re[ap]);
        }
    }
    __syncthreads();

    // L2: rows of 1024 (a1'): FFT-8 over b (stride 128), twiddle W_1024^(u*b')
    {
        const int a1 = t >> 7, u = t & 127;
        const int base = a1 * 1024;
        float re[8], im[8];
#pragma unroll
        for (int b = 0; b < 8; ++b) {
            const float2 v = buf[SW(base + 128 * b + u)];
            re[brev_c(b, 3)] = v.x; im[brev_c(b, 3)] = v.y;
        }
        fft8_reg(re, im);
#pragma unroll
        for (int bp = 0; bp < 8; ++bp) {
            const float ang = (-2.0f * PI_F / 1024.0f) * (float)(u * bp);
            const float cw = __cosf(ang), sw = __sinf(ang);
            buf[SW(base + bp * 128 + u)] =
                make_float2(cw * re[bp] - sw * im[bp], cw * im[bp] + sw * re[bp]);
        }
    }
    __syncthreads();

    // L3: sub-rows of 128 (a1',b'): FFT-8 over c (stride 16), twiddle W_128^(v*c')
    {
        const int a1 = t >> 7, b2 = (t >> 4) & 7, v0 = t & 15;
        const int base = a1 * 1024 + b2 * 128;
        float re[8], im[8];
#pragma unroll
        for (int c = 0; c < 8; ++c) {
            const float2 v = buf[SW(base + 16 * c + v0)];
            re[brev_c(c, 3)] = v.x; im[brev_c(c, 3)] = v.y;
        }
        fft8_reg(re, im);
#pragma unroll
        for (int cp = 0; cp < 8; ++cp) {
            const float ang = (-2.0f * PI_F / 128.0f) * (float)(v0 * cp);
            const float cw = __cosf(ang), sw = __sinf(ang);
            buf[SW(base + cp * 16 + v0)] =
                make_float2(cw * re[cp] - sw * im[cp], cw * im[cp] + sw * re[cp]);
        }
    }
    __syncthreads();

    // L4: 512 sub-blocks of 16: FFT-16 over v; scatter X[a1' + 8a2' + 64a3' + 512v']
    {
        float re[16], im[16];
        const int a1 = t >> 6, a2 = (t >> 3) & 7, a3 = t & 7;
        const int base = a1 * 1024 + a2 * 128 + a3 * 16;
        const int kb = a1 + 8 * a2 + 64 * a3;
        if (t < 512) {
#pragma unroll
            for (int v = 0; v < 16; ++v) {
                const float2 x = buf[SW(base + v)];
                re[brev_c(v, 4)] = x.x; im[brev_c(v, 4)] = x.y;
            }
        }
        __syncthreads();
        if (t < 512) {
            fft16_reg(re, im);
#pragma unroll
            for (int vp = 0; vp < 16; ++vp) {
                buf[SW(kb + 512 * vp)] = make_float2(re[vp], im[vp]);
            }
        }
        __syncthreads();
    }

    // store packed (Hr, -Hi), coalesced
    unsigned int* out = Hc + (size_t)row * NCOL;
#pragma unroll
    for (int e = 0; e < 8; ++e) {
        const int c = t + 1024 * e;
        const float2 v = buf[SW(c)];
        const unsigned int idx = (unsigned int)(row * NCOL + c);
        if (idx < out_uints)
            out[c] = (unsigned int)f2bf(v.x) |
                     (((unsigned int)f2bf(v.y) ^ 0x8000u) << 16);
    }
}

// ===========================================================================
// K3: transpose Hc[256][8192] (in d_out) -> Hc_t[8192][256] (ws + HT_OFF)
// ===========================================================================
__global__ __launch_bounds__(256) void transpose_H(const unsigned int* __restrict__ Hc,
                                                   unsigned int* __restrict__ ws,
                                                   unsigned int ws_uints) {
    __shared__ unsigned int tile[32][33];
    const int c0 = blockIdx.x * 32;   // column tile (n_col dim)
    const int k0 = blockIdx.y * 32;   // row tile (rank dim)
    const int tx = threadIdx.x & 31;
    const int ty = threadIdx.x >> 5;  // 0..7

#pragma unroll
    for (int e = 0; e < 4; ++e) {
        const int k = ty + e * 8;
        tile[k][tx] = Hc[(size_t)(k0 + k) * NCOL + c0 + tx];
    }
    __syncthreads();
#pragma unroll
    for (int e = 0; e < 4; ++e) {
        const int c = ty + e * 8;
        const unsigned int idx = HT_OFF + (unsigned int)(c0 + c) * RANKN + k0 + tx;
        if (idx < ws_uints) ws[idx] = tile[tx][c];
    }
}

// ===========================================================================
// K4: 256x256 phase-split GEMM. ReC[4096,8192] f32 = A2[4096,512]bf16 @
// Hc_t[8192,512]^T. BK=64, 512 thr (8 waves 2Mx4N, wave tile 128x64),
// 16x16x32 bf16 MFMA, 8x4 frags/wave.
//   T1: XCD-aware bijective block swizzle (nwg=512, 512%8==0)
//   T2: LDS xor-swizzle c16^=(row&7): global_load_lds dest stays LINEAR,
//       source address pre-inverse-swizzled, ds_read applies same xor
//       (both-sides-or-neither, rule #21)
//   T3/T4: depth-2 K-tile pipeline, counted vmcnt(8) in main loop (never 0),
//       stage t+2 issued only after the closing barrier of tile t's reads
//   T5: s_setprio(1) around each 16-MFMA cluster
// LDS = 2buf x (A 32KB + B 32KB) = 128 KB -> 1 block/CU, 2 waves/SIMD.
// ===========================================================================
#define GBM 256
#define GBK 64

__device__ static inline void load16_to_lds(const unsigned int* g, void* l) {
    __builtin_amdgcn_global_load_lds(
        (const __attribute__((address_space(1))) unsigned int*)g,
        (__attribute__((address_space(3))) unsigned int*)l,
        16, 0, 0);
}

// Stage K-tile t (A and B) into buffer: 4+4 global_load_lds (16B) per thread,
// 8 vmem insts per wave. LDS dest linear: slot s = l*512+tid (16B units),
// row = s>>3, c16 = s&7. Source column unit = c16 ^ (row&7) (inverse swizzle).
__device__ static inline void stage_tile(const unsigned int* __restrict__ ws,
                                         unsigned short* Ab, unsigned short* Bb,
                                         int tid, int j0, int n0, int t,
                                         unsigned int clamp_u) {
#pragma unroll
    for (int l = 0; l < 4; ++l) {
        const int s   = l * 512 + tid;
        const int row = s >> 3;
        const int cs  = (s & 7) ^ (row & 7);
        unsigned int ua = (unsigned int)((j0 + row) * RANKN + t * 32 + cs * 4);
        unsigned int ub = (unsigned int)(HT_OFF + (n0 + row) * RANKN + t * 32 + cs * 4);
        ua = ua < clamp_u ? ua : clamp_u;
        ub = ub < clamp_u ? ub : clamp_u;
        const int lb = (l * 512 + (tid & ~63)) * 8;   // shorts (slot*16B)
        load16_to_lds(ws + ua, Ab + lb);
        load16_to_lds(ws + ub, Bb + lb);
    }
}

__global__ __launch_bounds__(512, 2) void gemm_real(const unsigned int* __restrict__ ws,
                                                    float* __restrict__ C,
                                                    unsigned int out_lim,
                                                    unsigned int clamp_u) {
    __shared__ unsigned short As[2][GBM * GBK];   // 2 x 32 KB
    __shared__ unsigned short Bs[2][GBM * GBK];   // 2 x 32 KB

    const int tid  = threadIdx.x;
    const int wv   = tid >> 6;          // 0..7
    const int lane = tid & 63;
    const int quad = lane >> 4;         // 0..3
    const int l16  = lane & 15;
    const int wm   = wv >> 2;           // 0..1  (M waves)
    const int wn   = wv & 3;            // 0..3  (N waves)
    const int swx  = l16 & 7;           // == row&7 for all fragment rows

    // T1: XCD-aware bijective swizzle of flattened wg id (512 % 8 == 0)
    const int wg  = blockIdx.y * 32 + blockIdx.x;
    const int swz = (wg & 7) * 64 + (wg >> 3);
    const int n0  = (swz & 31) * GBM;   // 32 N-tiles
    const int j0  = (swz >> 5) * GBM;   // 16 M-tiles

    floatx4 zero = {0.0f, 0.0f, 0.0f, 0.0f};
    floatx4 acc[8][4];
#pragma unroll
    for (int i = 0; i < 8; ++i)
#pragma unroll
        for (int j = 0; j < 4; ++j) acc[i][j] = zero;

    // fragment ds_read offsets (shorts), T2 swizzle folded in
    int arow[8], brow[4], kslot[2];
#pragma unroll
    for (int mi = 0; mi < 8; ++mi) arow[mi] = (wm * 128 + mi * 16 + l16) * GBK;
#pragma unroll
    for (int ni = 0; ni < 4; ++ni) brow[ni] = (wn * 64 + ni * 16 + l16) * GBK;
#pragma unroll
    for (int ks = 0; ks < 2; ++ks) kslot[ks] = ((ks * 4 + quad) ^ swx) * 8;

    // prologue: 2 K-tiles in flight (16 vmem/wave outstanding)
    stage_tile(ws, &As[0][0], &Bs[0][0], tid, j0, n0, 0, clamp_u);
    stage_tile(ws, &As[1][0], &Bs[1][0], tid, j0, n0, 1, clamp_u);

#pragma unroll 1
    for (int t = 0; t < 8; ++t) {
        const unsigned short* At = &As[t & 1][0];
        const unsigned short* Bt = &Bs[t & 1][0];

        // T4: counted wait -- stage(t) landed, stage(t+1) stays in flight
        if (t < 7) { asm volatile("s_waitcnt vmcnt(8)" ::: "memory"); }
        else       { asm volatile("s_waitcnt vmcnt(0)" ::: "memory"); }
        __builtin_amdgcn_sched_barrier(0);
        __builtin_amdgcn_s_barrier();
        __builtin_amdgcn_sched_barrier(0);

#pragma unroll
        for (int ks = 0; ks < 2; ++ks) {
            const int kof = kslot[ks];
            short8 bf[4];
#pragma unroll
            for (int h = 0; h < 2; ++h) {
                short8 af[4];
#pragma unroll
                for (int i = 0; i < 4; ++i)
                    af[i] = *(const short8*)&At[arow[h * 4 + i] + kof];
                if (h == 0) {
#pragma unroll
                    for (int i = 0; i < 4; ++i)
                        bf[i] = *(const short8*)&Bt[brow[i] + kof];
                }
                __builtin_amdgcn_s_barrier();
                asm volatile("s_waitcnt lgkmcnt(0)" ::: "memory");
                __builtin_amdgcn_sched_barrier(0);
                __builtin_amdgcn_s_setprio(1);
#pragma unroll
                for (int mi = 0; mi < 4; ++mi)
#pragma unroll
                    for (int ni = 0; ni < 4; ++ni)
                        acc[h * 4 + mi][ni] = __builtin_amdgcn_mfma_f32_16x16x32_bf16(
                            af[mi], bf[ni], acc[h * 4 + mi][ni], 0, 0, 0);
                __builtin_amdgcn_s_setprio(0);
                __builtin_amdgcn_sched_barrier(0);
                __builtin_amdgcn_s_barrier();
            }
        }
        // all waves past their reads of buf (t&1): safe to overwrite it
        if (t < 6)
            stage_tile(ws, &As[t & 1][0], &Bs[t & 1][0], tid, j0, n0, t + 2, clamp_u);
    }

    // epilogue: C/D layout col=lane&15, row=quad*4+reg (m89-verified), guarded
#pragma unroll
    for (int mi = 0; mi < 8; ++mi) {
#pragma unroll
        for (int ni = 0; ni < 4; ++ni) {
            const int row = j0 + wm * 128 + mi * 16 + quad * 4;
            const int col = n0 + wn * 64 + ni * 16 + l16;
#pragma unroll
            for (int r = 0; r < 4; ++r) {
                const unsigned int idx = (unsigned int)((row + r) * NCOL + col);
                if (idx < out_lim) C[idx] = acc[mi][ni][r];
            }
        }
    }
}

// ===========================================================================
extern "C" void kernel_launch(void* const* d_in, const int* in_sizes, int n_in,
                              void* d_out, int out_size, void* d_ws, size_t ws_size,
                              hipStream_t stream) {
    const float* W   = (const float*)d_in[0];   // [4096, 256]
    const float* H   = (const float*)d_in[1];   // [256, 8192]
    const float* tau = (const float*)d_in[2];   // [4096, 256]
    float* out = (float*)d_out;                 // [4096, 8192] f32 (real part)

    unsigned int* ws = (unsigned int*)d_ws;
    const unsigned int ws_uints = (unsigned int)(ws_size / 4);
    const unsigned int clamp_u  = ws_uints >= 4 ? ws_uints - 4 : 0;  // 16B-load clamp
    unsigned int* HcOut = (unsigned int*)d_out;  // Ht staged in d_out[0..2M uints)

    make_A<<<NROW, RANKN, 0, stream>>>(W, tau, ws, ws_uints);
    fft_H<<<RANKN, 1024, 0, stream>>>(H, HcOut, (unsigned int)out_size);
    transpose_H<<<dim3(NCOL / 32, RANKN / 32), 256, 0, stream>>>(HcOut, ws, ws_uints);
    gemm_real<<<dim3(NCOL / 128 / 2, NROW / 128 / 2), 512, 0, stream>>>(
        ws, out, (unsigned int)out_size, clamp_u);
}